// Round 11
// baseline (499.548 us; speedup 1.0000x reference)
//
#include <hip/hip_runtime.h>
#include <cstddef>

// Problem constants (fixed by setup_inputs)
#define NN   20000     // nodes
#define FEAT 128
#define NH   8         // heads layer 1
#define NE   200000    // edges
#define EE   220000    // edges + self loops

typedef _Float16 f16;
typedef _Float16 f16x2 __attribute__((ext_vector_type(2)));
typedef _Float16 f16x8 __attribute__((ext_vector_type(8)));
typedef float    f32x4 __attribute__((ext_vector_type(4)));

__device__ __forceinline__ float lrelu(float a) { return a > 0.f ? a : 0.2f * a; }

// ================= preambleA: parallel-friendly input-only precompute ================
// [0,PA0) count_deg | [PA0,PA1) maxpool | [PA1,PA2) W1t+xph | [PA2,PA3) small_vec
#define PA0 782
#define PA1 (PA0 + 782)
#define PA2 (PA1 + 10064)
#define PA3 (PA2 + 10)
__global__ __launch_bounds__(256) void preambleA(
    const int* __restrict__ ei, const float* __restrict__ syn,
    const float* __restrict__ W1, const float* __restrict__ xparam,
    const float* __restrict__ W2, const float* __restrict__ Wc1,
    const float* __restrict__ b2, const float* __restrict__ be2,
    const float* __restrict__ as2, const float* __restrict__ ad2,
    int* __restrict__ dL, int* __restrict__ dR,
    float* __restrict__ xp, f16* __restrict__ W1t, f16* __restrict__ xph,
    float* __restrict__ vB, float* __restrict__ vL, float* __restrict__ vR,
    float* __restrict__ ws2, float* __restrict__ wd2)
{
  __shared__ float smem[1056];
  const int b = blockIdx.x, t = threadIdx.x;
  if (b < PA0) {                                   // ---- count_deg ----
    int e = b * 256 + t;
    if (e >= NE) return;
    atomicAdd(&dL[ei[e]], 1);
    atomicAdd(&dR[ei[NE + e]], 1);
  } else if (b < PA1) {                            // ---- synapse maxpool ----
    int e = (b - PA0) * 256 + t;
    if (e >= NE) return;
    const float* p = syn + (size_t)e * 24;
    float v[24];
#pragma unroll
    for (int i = 0; i < 6; i++) {
      float4 q = *(const float4*)(p + i * 4);
      v[i*4+0] = q.x; v[i*4+1] = q.y; v[i*4+2] = q.z; v[i*4+3] = q.w;
    }
#pragma unroll
    for (int dd = 0; dd < 6; dd++)
      xp[(size_t)e * 6 + dd] = fmaxf(fmaxf(v[dd], v[6 + dd]), fmaxf(v[12 + dd], v[18 + dd]));
  } else if (b < PA2) {                            // ---- W1 transpose-cvt + xph cvt ----
    int bb = b - PA1;
    if (bb < 64) {
      float (*tile)[33] = (float(*)[33])smem;
      const int n0 = (bb & 15) * 32, k0 = (bb >> 4) * 32;
      const int tx = t & 31, ty = t >> 5;
#pragma unroll
      for (int i = 0; i < 4; i++)
        tile[ty + i * 8][tx] = W1[(size_t)(k0 + ty + i * 8) * 512 + n0 + tx];
      __syncthreads();
#pragma unroll
      for (int i = 0; i < 4; i++)
        W1t[(size_t)(n0 + ty + i * 8) * 128 + k0 + tx] = (f16)tile[tx][ty + i * 8];
    } else {
      int idx = (bb - 64) * 256 + t;               // NN*FEAT = 10000*256 exact
      xph[idx] = (f16)xparam[idx];
    }
  } else {                                         // ---- small_vec ----
    int g = (b - PA2) * 256 + t;
    int seg = g >> 9, j = g & 511;
    float a = 0.f;
    if (seg == 0) {
      for (int k = 0; k < 512; k++) a = fmaf(b2[k], Wc1[(size_t)k * 512 + j], a);
      vB[j] = a;
    } else if (seg == 1) {
      for (int k = 0; k < 512; k++) a = fmaf(be2[k], Wc1[(size_t)(512 + k) * 512 + j], a);
      vL[j] = a;
    } else if (seg == 2) {
      for (int k = 0; k < 512; k++) a = fmaf(be2[k], Wc1[(size_t)(1024 + k) * 512 + j], a);
      vR[j] = a;
    } else if (seg == 3) {
      for (int c = 0; c < 512; c++) a = fmaf(W2[(size_t)j * 512 + c], as2[c], a);
      ws2[j] = a;
    } else {
      for (int c = 0; c < 512; c++) a = fmaf(W2[(size_t)j * 512 + c], ad2[c], a);
      wd2[j] = a;
    }
  }
}

// ================= fused1: xl1 GEMM + fused attn1 dots | h1 gather (16 nodes/blk) ====
__global__ __launch_bounds__(256) void fused1(
    const f16* __restrict__ xph, const f16* __restrict__ W1t, f16* __restrict__ xl1h,
    const float* __restrict__ as1, const float* __restrict__ ad1,
    float* __restrict__ s1, float* __restrict__ d1,
    const float* __restrict__ xp, const float* __restrict__ We1,
    const float* __restrict__ be1,
    const int* __restrict__ oL, const int* __restrict__ eL,
    const int* __restrict__ oR, const int* __restrict__ eR,
    f16* __restrict__ hlrh)
{
  __shared__ __align__(16) f16 smem[8320];     // 16640 B: GEMM As/Bs then C-tile[64][130]
  const int t = threadIdx.x;
  if (blockIdx.x < 1252) {
    // ---- MFMA GEMM: xl1h = xph[NN,128] @ W1t[512,128]^T; epilogue computes s1/d1 ----
    f16 (*As)[40] = (f16(*)[40])smem;
    f16 (*Bs)[40] = (f16(*)[40])(smem + 64 * 40);
    const int wave = t >> 6, lane = t & 63;
    const int quad = lane >> 4, mrow = lane & 15;
    const int m0 = (blockIdx.x >> 2) * 64, n0 = (blockIdx.x & 3) * 128;
    f32x4 acc[4][2];
    f32x4 zero4 = {0.f, 0.f, 0.f, 0.f};
#pragma unroll
    for (int i = 0; i < 4; i++)
#pragma unroll
      for (int j = 0; j < 2; j++) acc[i][j] = zero4;
    const int ar = t >> 2, ac = (t & 3) * 8;
    for (int k0 = 0; k0 < FEAT; k0 += 32) {
      {
        int gm = m0 + ar;
        f16x8 v = {0, 0, 0, 0, 0, 0, 0, 0};
        if (gm < NN) v = *(const f16x8*)(xph + (size_t)gm * FEAT + k0 + ac);
        *(f16x8*)&As[ar][ac] = v;
      }
#pragma unroll
      for (int i = 0; i < 2; i++) {
        int idx = t + i * 256;
        int r = idx >> 2, c = (idx & 3) * 8;
        *(f16x8*)&Bs[r][c] = *(const f16x8*)(W1t + (size_t)(n0 + r) * FEAT + k0 + c);
      }
      __syncthreads();
      f16x8 af[4], bf[2];
#pragma unroll
      for (int mt = 0; mt < 4; mt++) af[mt] = *(const f16x8*)&As[mt * 16 + mrow][quad * 8];
#pragma unroll
      for (int nt = 0; nt < 2; nt++) bf[nt] = *(const f16x8*)&Bs[wave * 32 + nt * 16 + mrow][quad * 8];
#pragma unroll
      for (int mt = 0; mt < 4; mt++)
#pragma unroll
        for (int nt = 0; nt < 2; nt++)
          acc[mt][nt] = __builtin_amdgcn_mfma_f32_16x16x32_f16(af[mt], bf[nt], acc[mt][nt], 0, 0, 0);
      __syncthreads();
    }
    f16 (*tile)[130] = (f16(*)[130])smem;       // reuse As/Bs space (done with them)
#pragma unroll
    for (int mt = 0; mt < 4; mt++)
#pragma unroll
      for (int nt = 0; nt < 2; nt++) {
        int cl = wave * 32 + nt * 16 + mrow;
        int col = n0 + cl;
#pragma unroll
        for (int reg = 0; reg < 4; reg++) {
          int rl = mt * 16 + quad * 4 + reg;
          int row = m0 + rl;
          f16 cv = (f16)acc[mt][nt][reg];
          tile[rl][cl] = cv;
          if (row < NN) xl1h[(size_t)row * 512 + col] = cv;
        }
      }
    __syncthreads();
    // dots: 128 (row, head-local) pairs; 2 threads each sum 32 cols
    {
      int pair = t >> 1, half = t & 1;
      int rl = pair & 63, hl = pair >> 6;
      int h = (n0 >> 6) + hl;
      const float* a1 = as1 + h * 64 + half * 32;
      const float* a2 = ad1 + h * 64 + half * 32;
      const f16* trow = &tile[rl][hl * 64 + half * 32];
      float ssum = 0.f, dsum = 0.f;
#pragma unroll 8
      for (int j = 0; j < 32; j++) {
        float v = (float)trow[j];
        ssum += v * a1[j];
        dsum += v * a2[j];
      }
      ssum += __shfl_down(ssum, 1);
      dsum += __shfl_down(dsum, 1);
      int row = m0 + rl;
      if (!half && row < NN) { s1[row * 8 + h] = ssum; d1[row * 8 + h] = dsum; }
    }
  } else {
    // ---- h1 mean-gather: 16 (node,side) per block, packed f16x2 over edge pairs -----
    int* lst_s  = (int*)smem;            // 32 ints
    f16x2* xs2  = (f16x2*)(smem + 128);  // 16 pairs x 6 cols
    const int c = t;
    f16x2 w[6], bb2, zero2;
#pragma unroll
    for (int j = 0; j < 6; j++) { f16 wv = (f16)We1[j * 256 + c]; w[j][0] = wv; w[j][1] = wv; }
    { f16 bv = (f16)be1[c]; bb2[0] = bv; bb2[1] = bv; }
    zero2[0] = (f16)0.f; zero2[1] = (f16)0.f;
    const int b0 = (blockIdx.x - 1252) * 16;
    for (int q = 0; q < 16; q++) {
      const int b = b0 + q;
      const int* off; const int* lst; int n;
      if (b < NN) { off = oL; lst = eL; n = b; } else { off = oR; lst = eR; n = b - NN; }
      const int beg = off[n], end = off[n + 1], deg = end - beg;
      f16x2 acc2 = zero2;
      float accT = 0.f;
      for (int base = 0; base < deg; base += 32) {
        int m = min(32, deg - base);
        if (c < 32) lst_s[c] = (c < m) ? lst[beg + base + c] : 0;
        __syncthreads();
        if (c < 96) {
          int j = c / 6, cc = c - j * 6;
          int e0 = 2 * j, e1 = 2 * j + 1;
          float v0 = (e0 < m) ? xp[(size_t)lst_s[e0] * 6 + cc] : 0.f;
          float v1 = (e1 < m) ? xp[(size_t)lst_s[e1] * 6 + cc] : 0.f;
          f16x2 pr; pr[0] = (f16)v0; pr[1] = (f16)v1;
          xs2[j * 6 + cc] = pr;
        }
        __syncthreads();
        int mp = m >> 1;
        for (int k = 0; k < mp; k++) {
          f16x2 v = bb2;
#pragma unroll
          for (int j = 0; j < 6; j++) v = xs2[k * 6 + j] * w[j] + v;
          f16x2 r;
          r[0] = v[0] > (f16)0.f ? v[0] : (f16)0.f;
          r[1] = v[1] > (f16)0.f ? v[1] : (f16)0.f;
          acc2 = acc2 + r;
        }
        if (m & 1) {
          float v = (float)bb2[0];
#pragma unroll
          for (int j = 0; j < 6; j++) v = fmaf((float)xs2[mp * 6 + j][0], (float)w[j][0], v);
          accT += fmaxf(v, 0.f);
        }
        __syncthreads();
      }
      float accf = (float)acc2[0] + (float)acc2[1] + accT;
      hlrh[(size_t)b * 256 + c] = (f16)(deg > 0 ? accf / (float)deg : 0.f);
    }
  }
}

// ================= mid: gat_gather1 (+fused attn2 dots) | gemm3in1 | Wc2t ============
// blocks [0,NN) gather1 | [NN,NN+128) gemm3in1 | [NN+128,NN+208) Wc2t
__global__ __launch_bounds__(256) void mid_kernel(
    const int* __restrict__ snA, const int* __restrict__ offA,
    const float* __restrict__ s1, const float* __restrict__ d1,
    const f16* __restrict__ xlh, const float* __restrict__ b1,
    const float* __restrict__ ws2, const float* __restrict__ wd2,
    f16* __restrict__ x1h, float* __restrict__ s2, float* __restrict__ d2,
    const float* __restrict__ W2, const float* __restrict__ We2,
    const float* __restrict__ Wc1, f16* __restrict__ WzAt, f16* __restrict__ McatT,
    const float* __restrict__ Wc2, f16* __restrict__ Wc2t)
{
  __shared__ float smem[2112];                 // 8448 B, aliased per range
  const int t = threadIdx.x;
  if (blockIdx.x < NN) {
    // ---- gather1 with fused softmax-weight compute + attn2 dots ----
    int* sns   = (int*)smem;                   // 32
    float* wls = smem + 32;                    // 256
    float* red = smem + 288;                   // 256
    float* redD= smem + 544;                   // 256
    const int n = blockIdx.x;
    const int hw = t & 7;
    const int slot = t >> 3;
    const int hf = t >> 5;
    const int beg = offA[n], end = offA[n + 1];
    const int deg = end - beg;
    const float dnw = d1[n * 8 + hw];
    float a0 = 0.f, a1v = 0.f, denp = 0.f;
    for (int base = 0; base < deg; base += 32) {
      int m = min(32, deg - base);
      if (t < 32) sns[t] = (t < m) ? snA[beg + base + t] : 0;
      __syncthreads();
      {
        float w = 0.f;
        if (slot < m) w = __expf(lrelu(s1[sns[slot] * 8 + hw] + dnw));
        wls[t] = w;
        denp += w;
      }
      __syncthreads();
      int m8 = (m + 7) & ~7;
      for (int k = 0; k < m8; k += 8) {
        int ss[8]; float ww[8]; f16x2 pp[8];
#pragma unroll
        for (int u = 0; u < 8; u++) { ss[u] = sns[k + u]; ww[u] = wls[(k + u) * 8 + hf]; }
#pragma unroll
        for (int u = 0; u < 8; u++) pp[u] = *(const f16x2*)(xlh + (size_t)ss[u] * 512 + 2 * t);
#pragma unroll
        for (int u = 0; u < 8; u++) {
          a0  = fmaf(ww[u], (float)pp[u][0], a0);
          a1v = fmaf(ww[u], (float)pp[u][1], a1v);
        }
      }
      __syncthreads();
    }
    red[t] = denp;
    __syncthreads();
    for (int off = 128; off >= 8; off >>= 1) {
      if (t < off) red[t] += red[t + off];
      __syncthreads();
    }
    float rh = 1.f / (red[hf] + 1e-16f);
    __syncthreads();
    float v0 = a0 * rh + b1[2 * t], v1 = a1v * rh + b1[2 * t + 1];
    v0 = v0 > 0.f ? v0 : (__expf(v0) - 1.f);
    v1 = v1 > 0.f ? v1 : (__expf(v1) - 1.f);
    f16x2 o; o[0] = (f16)v0; o[1] = (f16)v1;
    *(f16x2*)(x1h + (size_t)n * 512 + 2 * t) = o;
    red[t]  = v0 * ws2[2 * t] + v1 * ws2[2 * t + 1];
    redD[t] = v0 * wd2[2 * t] + v1 * wd2[2 * t + 1];
    __syncthreads();
    for (int off = 128; off > 0; off >>= 1) {
      if (t < off) { red[t] += red[t + off]; redD[t] += redD[t + off]; }
      __syncthreads();
    }
    if (t == 0) { s2[n] = red[0]; d2[n] = redD[0]; }
  } else if (blockIdx.x < NN + 128) {
    // ---- gemm3in1 (folded weights; hot clocks; hides under gather1) ----
    float (*As)[68] = (float(*)[68])smem;
    float (*Bs)[64] = (float(*)[64])(smem + 16 * 68);
    const int bb = blockIdx.x - NN;
    const float* A; const float* B; f16* dst; int dstOff, m0, n0;
    if (bb < 64)      { A = W2;  B = Wc1;  dst = WzAt;  dstOff = 0;
                        m0 = (bb >> 3) * 64; n0 = (bb & 7) * 64; }
    else if (bb < 96) { int i = bb - 64; A = We2; B = Wc1 + (size_t)512 * 512;
                        dst = McatT; dstOff = 0;
                        m0 = (i >> 3) * 64; n0 = (i & 7) * 64; }
    else              { int i = bb - 96; A = We2; B = Wc1 + (size_t)1024 * 512;
                        dst = McatT; dstOff = 256;
                        m0 = (i >> 3) * 64; n0 = (i & 7) * 64; }
    const int tx = t & 15, ty = t >> 4;
    float acc[4][4] = {{0.f}};
    float pa[4], pb[4];
#pragma unroll
    for (int i = 0; i < 4; i++) {
      int idx = t + i * 256;
      pa[i] = A[(size_t)(m0 + (idx >> 4)) * 512 + (idx & 15)];
      pb[i] = B[(size_t)(idx >> 6) * 512 + n0 + (idx & 63)];
    }
    for (int k0 = 0; k0 < 512; k0 += 16) {
#pragma unroll
      for (int i = 0; i < 4; i++) {
        int idx = t + i * 256;
        As[idx & 15][idx >> 4] = pa[i];
        Bs[idx >> 6][idx & 63] = pb[i];
      }
      __syncthreads();
      if (k0 + 16 < 512) {
        int kn = k0 + 16;
#pragma unroll
        for (int i = 0; i < 4; i++) {
          int idx = t + i * 256;
          pa[i] = A[(size_t)(m0 + (idx >> 4)) * 512 + kn + (idx & 15)];
          pb[i] = B[(size_t)(kn + (idx >> 6)) * 512 + n0 + (idx & 63)];
        }
      }
#pragma unroll
      for (int kk = 0; kk < 16; kk++) {
        float4 a4 = *(const float4*)&As[kk][ty * 4];
        float4 b4 = *(const float4*)&Bs[kk][tx * 4];
        float av[4] = {a4.x, a4.y, a4.z, a4.w};
        float bv[4] = {b4.x, b4.y, b4.z, b4.w};
#pragma unroll
        for (int i = 0; i < 4; i++)
#pragma unroll
          for (int j = 0; j < 4; j++) acc[i][j] = fmaf(av[i], bv[j], acc[i][j]);
      }
      __syncthreads();
    }
#pragma unroll
    for (int i = 0; i < 4; i++)
#pragma unroll
      for (int j = 0; j < 4; j++)
        dst[(size_t)(n0 + tx * 4 + j) * 512 + dstOff + m0 + ty * 4 + i] = (f16)acc[i][j];
  } else {
    // ---- Wc2 transpose-cvt ----
    float (*tile)[33] = (float(*)[33])smem;
    int i0 = blockIdx.x - NN - 128;              // 80 blocks: 5 n-tiles x 16 k-tiles
    const int n0 = (i0 % 5) * 32, k0 = (i0 / 5) * 32;
    const int tx = t & 31, ty = t >> 5;
#pragma unroll
    for (int i = 0; i < 4; i++) {
      int k = k0 + ty + i * 8, n = n0 + tx;
      tile[ty + i * 8][tx] = (n < 133) ? Wc2[(size_t)k * 133 + n] : 0.f;
    }
    __syncthreads();
#pragma unroll
    for (int i = 0; i < 4; i++) {
      int n = n0 + ty + i * 8, k = k0 + tx;
      if (n < 133) Wc2t[(size_t)n * 512 + k] = (f16)tile[tx][ty + i * 8];
    }
  }
}

// ================= fused2: z-GEMM + class_pre (both MFMA) ============================
__global__ __launch_bounds__(256) void fused2(
    const f16* __restrict__ x1h, const f16* __restrict__ WzAt, f16* __restrict__ zh,
    const f16* __restrict__ hlrh, const f16* __restrict__ McatT,
    const int* __restrict__ degL, const int* __restrict__ degR,
    const float* __restrict__ bc1, const float* __restrict__ vB,
    const float* __restrict__ vL, const float* __restrict__ vR, f16* __restrict__ Ph)
{
  __shared__ __align__(16) f16 smem[7680];
  const int t = threadIdx.x;
  f16 (*As)[40] = (f16(*)[40])smem;
  f16 (*Bs)[40] = (f16(*)[40])(smem + 64 * 40);
  const bool isZ = blockIdx.x < 1252;
  const int bb = isZ ? blockIdx.x : blockIdx.x - 1252;
  const int wave = t >> 6, lane = t & 63;
  const int quad = lane >> 4, mrow = lane & 15;
  const int m0 = (bb >> 2) * 64, n0 = (bb & 3) * 128;
  f32x4 acc[4][2];
  f32x4 zero4 = {0.f, 0.f, 0.f, 0.f};
#pragma unroll
  for (int i = 0; i < 4; i++)
#pragma unroll
    for (int j = 0; j < 2; j++) acc[i][j] = zero4;
  const int ar = t >> 2, ac = (t & 3) * 8;
  const f16* Bt = isZ ? WzAt : McatT;
  for (int k0 = 0; k0 < 512; k0 += 32) {
    {
      int gm = m0 + ar;
      f16x8 v = {0, 0, 0, 0, 0, 0, 0, 0};
      if (gm < NN) {
        if (isZ) v = *(const f16x8*)(x1h + (size_t)gm * 512 + k0 + ac);
        else {
          size_t row = (k0 >> 8) ? (size_t)(NN + gm) : (size_t)gm;
          v = *(const f16x8*)(hlrh + row * 256 + (k0 & 255) + ac);
        }
      }
      *(f16x8*)&As[ar][ac] = v;
    }
#pragma unroll
    for (int i = 0; i < 2; i++) {
      int idx = t + i * 256;
      int r = idx >> 2, c = (idx & 3) * 8;
      *(f16x8*)&Bs[r][c] = *(const f16x8*)(Bt + (size_t)(n0 + r) * 512 + k0 + c);
    }
    __syncthreads();
    f16x8 af[4], bf[2];
#pragma unroll
    for (int mt = 0; mt < 4; mt++) af[mt] = *(const f16x8*)&As[mt * 16 + mrow][quad * 8];
#pragma unroll
    for (int nt = 0; nt < 2; nt++) bf[nt] = *(const f16x8*)&Bs[wave * 32 + nt * 16 + mrow][quad * 8];
#pragma unroll
    for (int mt = 0; mt < 4; mt++)
#pragma unroll
      for (int nt = 0; nt < 2; nt++)
        acc[mt][nt] = __builtin_amdgcn_mfma_f32_16x16x32_f16(af[mt], bf[nt], acc[mt][nt], 0, 0, 0);
    __syncthreads();
  }
  if (isZ) {
#pragma unroll
    for (int mt = 0; mt < 4; mt++)
#pragma unroll
      for (int nt = 0; nt < 2; nt++) {
        int col = n0 + wave * 32 + nt * 16 + mrow;
#pragma unroll
        for (int reg = 0; reg < 4; reg++) {
          int row = m0 + mt * 16 + quad * 4 + reg;
          if (row < NN) zh[(size_t)row * 512 + col] = (f16)acc[mt][nt][reg];
        }
      }
  } else {
#pragma unroll
    for (int mt = 0; mt < 4; mt++)
#pragma unroll
      for (int nt = 0; nt < 2; nt++) {
        int col = n0 + wave * 32 + nt * 16 + mrow;
        float bb2 = bc1[col] + vB[col];
        float vl = vL[col], vr = vR[col];
#pragma unroll
        for (int reg = 0; reg < 4; reg++) {
          int row = m0 + mt * 16 + quad * 4 + reg;
          if (row >= NN) continue;
          float v = acc[mt][nt][reg] + bb2;
          if (degL[row] > 0) v += vl;
          if (degR[row] > 0) v += vr;
          Ph[(size_t)row * 512 + col] = (f16)v;
        }
      }
  }
}

// ---------------- MFMA output GEMM: out(f32)[M,133] = h2h @ Wc2t^T + bc2 -------------
__global__ __launch_bounds__(256) void mfma_out(
    const f16* __restrict__ A, const f16* __restrict__ Bt,
    const float* __restrict__ bias, float* __restrict__ C, int M)
{
  __shared__ __align__(16) f16 As[64][40];
  __shared__ __align__(16) f16 Bs[128][40];
  const int t = threadIdx.x;
  const int wave = t >> 6, lane = t & 63;
  const int quad = lane >> 4, mrow = lane & 15;
  const int m0 = blockIdx.y * 64, n0 = blockIdx.x * 128;
  f32x4 acc[4][2];
  f32x4 zero4 = {0.f, 0.f, 0.f, 0.f};
#pragma unroll
  for (int i = 0; i < 4; i++)
#pragma unroll
    for (int j = 0; j < 2; j++) acc[i][j] = zero4;
  const int ar = t >> 2, ac = (t & 3) * 8;
  for (int k0 = 0; k0 < 512; k0 += 32) {
    {
      int gm = m0 + ar;
      f16x8 v = {0, 0, 0, 0, 0, 0, 0, 0};
      if (gm < M) v = *(const f16x8*)(A + (size_t)gm * 512 + k0 + ac);
      *(f16x8*)&As[ar][ac] = v;
    }
#pragma unroll
    for (int i = 0; i < 2; i++) {
      int idx = t + i * 256;
      int r = idx >> 2, c = (idx & 3) * 8;
      f16x8 v = {0, 0, 0, 0, 0, 0, 0, 0};
      if (n0 + r < 133) v = *(const f16x8*)(Bt + (size_t)(n0 + r) * 512 + k0 + c);
      *(f16x8*)&Bs[r][c] = v;
    }
    __syncthreads();
    f16x8 af[4], bf[2];
#pragma unroll
    for (int mt = 0; mt < 4; mt++) af[mt] = *(const f16x8*)&As[mt * 16 + mrow][quad * 8];
#pragma unroll
    for (int nt = 0; nt < 2; nt++) bf[nt] = *(const f16x8*)&Bs[wave * 32 + nt * 16 + mrow][quad * 8];
#pragma unroll
    for (int mt = 0; mt < 4; mt++)
#pragma unroll
      for (int nt = 0; nt < 2; nt++)
        acc[mt][nt] = __builtin_amdgcn_mfma_f32_16x16x32_f16(af[mt], bf[nt], acc[mt][nt], 0, 0, 0);
    __syncthreads();
  }
#pragma unroll
  for (int mt = 0; mt < 4; mt++)
#pragma unroll
    for (int nt = 0; nt < 2; nt++) {
      int col = n0 + wave * 32 + nt * 16 + mrow;
      if (col >= 133) continue;
      float bb = bias[col];
#pragma unroll
      for (int reg = 0; reg < 4; reg++) {
        int row = m0 + mt * 16 + quad * 4 + reg;
        if (row < M) C[(size_t)row * 133 + col] = acc[mt][nt][reg] + bb;
      }
    }
}

// ------------- CSR scan (2 blocks; offA derived as offR + n) -------------------------
__global__ __launch_bounds__(1024) void scan_csr(
    const int* __restrict__ dL, const int* __restrict__ dR,
    int* __restrict__ oL, int* __restrict__ oR, int* __restrict__ oA)
{
  const int b = blockIdx.x;
  const int* deg = b == 0 ? dL : dR;
  __shared__ int part[1024];
  const int t = threadIdx.x;
  const int chunk = 20;
  int base = t * chunk;
  int sum = 0;
  for (int i = 0; i < chunk; i++) { int idx = base + i; if (idx < NN) sum += deg[idx]; }
  part[t] = sum;
  __syncthreads();
  for (int o = 1; o < 1024; o <<= 1) {
    int v = (t >= o) ? part[t - o] : 0;
    __syncthreads();
    part[t] += v;
    __syncthreads();
  }
  int run = part[t] - sum;
  if (b == 0) {
    for (int i = 0; i < chunk; i++) {
      int idx = base + i;
      if (idx < NN) { oL[idx] = run; run += deg[idx]; }
    }
    if (t == 0) oL[NN] = part[1023];
  } else {
    for (int i = 0; i < chunk; i++) {
      int idx = base + i;
      if (idx < NN) { oR[idx] = run; oA[idx] = run + idx; run += deg[idx]; }
    }
    if (t == 0) { oR[NN] = part[1023]; oA[NN] = part[1023] + NN; }
  }
}

// ------------- fill: 2 atomics/edge; self-loops atomic-free --------------------------
__global__ __launch_bounds__(256) void fill_csr(
    const int* __restrict__ ei,
    const int* __restrict__ oL, const int* __restrict__ oR, const int* __restrict__ oA,
    int* __restrict__ cL, int* __restrict__ cR,
    int* __restrict__ eL, int* __restrict__ eR, int* __restrict__ snA)
{
  int e = blockIdx.x * 256 + threadIdx.x;
  if (e >= EE) return;
  if (e < NE) {
    int s = ei[e], d = ei[NE + e];
    int p = atomicAdd(&cL[s], 1); eL[oL[s] + p] = e;
    p = atomicAdd(&cR[d], 1);
    eR[oR[d] + p] = e;
    snA[oA[d] + 1 + p] = s;       // A-segment: [selfloop, dst-edges...]
  } else {
    int n = e - NE;
    snA[oA[n]] = n;
  }
}

// ------------- GAT layer 2 gather with FUSED softmax-weight compute ------------------
__global__ __launch_bounds__(256) void gat_gather2(
    const int* __restrict__ snA, const int* __restrict__ offA,
    const float* __restrict__ s2, const float* __restrict__ d2,
    const f16* __restrict__ zh, const f16* __restrict__ Ph,
    f16* __restrict__ h2h)
{
  __shared__ int sns[32];
  __shared__ float wls[32];
  __shared__ float den_sh;
  const int n = blockIdx.x, t = threadIdx.x;
  const int beg = offA[n], end = offA[n + 1];
  const int deg = end - beg;
  const float dn = d2[n];
  float a0 = 0.f, a1v = 0.f, denp = 0.f;
  for (int base = 0; base < deg; base += 32) {
    int m = min(32, deg - base);
    if (t < 32) {
      int sn = (t < m) ? snA[beg + base + t] : 0;
      float w = (t < m) ? __expf(lrelu(s2[sn] + dn)) : 0.f;
      sns[t] = sn;
      wls[t] = w;
      denp += w;
    }
    __syncthreads();
    int m8 = (m + 7) & ~7;
    for (int k = 0; k < m8; k += 8) {
      int ss[8]; float ww[8]; f16x2 pp[8];
#pragma unroll
      for (int u = 0; u < 8; u++) { ss[u] = sns[k + u]; ww[u] = wls[k + u]; }
#pragma unroll
      for (int u = 0; u < 8; u++) pp[u] = *(const f16x2*)(zh + (size_t)ss[u] * 512 + 2 * t);
#pragma unroll
      for (int u = 0; u < 8; u++) {
        a0  = fmaf(ww[u], (float)pp[u][0], a0);
        a1v = fmaf(ww[u], (float)pp[u][1], a1v);
      }
    }
    __syncthreads();
  }
  if (t < 64) {
    denp += __shfl_xor(denp, 16);
    denp += __shfl_xor(denp, 8);
    denp += __shfl_xor(denp, 4);
    denp += __shfl_xor(denp, 2);
    denp += __shfl_xor(denp, 1);
    if (t == 0) den_sh = denp;
  }
  __syncthreads();
  float rn = 1.f / (den_sh + 1e-16f);
  f16x2 pv = *(const f16x2*)(Ph + (size_t)n * 512 + 2 * t);
  float v0 = fmaxf(a0  * rn + (float)pv[0], 0.f);
  float v1 = fmaxf(a1v * rn + (float)pv[1], 0.f);
  f16x2 o; o[0] = (f16)v0; o[1] = (f16)v1;
  *(f16x2*)(h2h + (size_t)n * 512 + 2 * t) = o;
}

extern "C" void kernel_launch(void* const* d_in, const int* in_sizes, int n_in,
                              void* d_out, int out_size, void* d_ws, size_t ws_size,
                              hipStream_t stream) {
  const int*   edge_index = (const int*)d_in[0];
  const float* synapse    = (const float*)d_in[2];
  const float* x_param = (const float*)d_in[5];
  const float* W1      = (const float*)d_in[6];
  const float* as1     = (const float*)d_in[7];
  const float* ad1     = (const float*)d_in[8];
  const float* b1      = (const float*)d_in[9];
  const float* W2      = (const float*)d_in[10];
  const float* as2     = (const float*)d_in[11];
  const float* ad2     = (const float*)d_in[12];
  const float* b2      = (const float*)d_in[13];
  const float* We1     = (const float*)d_in[14];
  const float* be1     = (const float*)d_in[15];
  const float* We2     = (const float*)d_in[16];
  const float* be2     = (const float*)d_in[17];
  const float* Wc1     = (const float*)d_in[18];
  const float* bc1     = (const float*)d_in[19];
  const float* Wc2     = (const float*)d_in[20];
  const float* bc2     = (const float*)d_in[21];
  float* out_p = (float*)d_out;

  // ---- workspace layout (~125 MB) ----
  char* p = (char*)d_ws;
  float* xp    = (float*)p; p += (size_t)NE * 6 * 4;
  float* s1    = (float*)p; p += (size_t)NN * 8 * 4;
  float* d1    = (float*)p; p += (size_t)NN * 8 * 4;
  float* s2    = (float*)p; p += (size_t)NN * 4;
  float* d2    = (float*)p; p += (size_t)NN * 4;
  float* vB    = (float*)p; p += 512 * 4;
  float* vL    = (float*)p; p += 512 * 4;
  float* vR    = (float*)p; p += 512 * 4;
  float* ws2   = (float*)p; p += 512 * 4;
  float* wd2   = (float*)p; p += 512 * 4;
  f16* xph     = (f16*)p; p += (size_t)NN * FEAT * 2;
  f16* xl1h    = (f16*)p; p += (size_t)NN * 512 * 2;
  f16* x1h     = (f16*)p; p += (size_t)NN * 512 * 2;
  f16* zh      = (f16*)p; p += (size_t)NN * 512 * 2;
  f16* h2h     = (f16*)p; p += (size_t)NN * 512 * 2;
  f16* Phb     = (f16*)p; p += (size_t)NN * 512 * 2;
  f16* hlrh    = (f16*)p; p += (size_t)2 * NN * 256 * 2;
  f16* W1t     = (f16*)p; p += (size_t)512 * FEAT * 2;
  f16* WzAt    = (f16*)p; p += (size_t)512 * 512 * 2;
  f16* McatT   = (f16*)p; p += (size_t)512 * 512 * 2;
  f16* Wc2t    = (f16*)p; p += (size_t)133 * 512 * 2;
  int* degL    = (int*)p;                 // N  (zero group start)
  int* degR    = degL + NN;               // N
  int* curL    = degR + NN;               // N
  int* curR    = curL + NN;               // N  (zero group: 4N ints)
  int* offL    = curR + NN;               // N+1
  int* offR    = offL + NN + 1;           // N+1
  int* offA    = offR + NN + 1;           // N+1
  int* edgeL   = offA + NN + 1;           // E
  int* edgeR   = edgeL + NE;              // E
  int* snA     = edgeR + NE;              // EE

  hipMemsetAsync(degL, 0, (size_t)4 * NN * sizeof(int), stream);

  preambleA<<<PA3, 256, 0, stream>>>(
      edge_index, synapse, W1, x_param, W2, Wc1, b2, be2, as2, ad2,
      degL, degR, xp, W1t, xph, vB, vL, vR, ws2, wd2);
  scan_csr<<<2, 1024, 0, stream>>>(degL, degR, offL, offR, offA);
  fill_csr<<<(EE + 255) / 256, 256, 0, stream>>>(edge_index, offL, offR, offA,
                                                 curL, curR, edgeL, edgeR, snA);
  fused1<<<1252 + 2500, 256, 0, stream>>>(xph, W1t, xl1h, as1, ad1, s1, d1,
                                          xp, We1, be1, offL, edgeL, offR, edgeR, hlrh);
  mid_kernel<<<NN + 208, 256, 0, stream>>>(snA, offA, s1, d1, xl1h, b1, ws2, wd2,
                                           x1h, s2, d2, W2, We2, Wc1, WzAt, McatT,
                                           Wc2, Wc2t);
  fused2<<<2504, 256, 0, stream>>>(x1h, WzAt, zh, hlrh, McatT,
                                   degL, degR, bc1, vB, vL, vR, Phb);
  gat_gather2<<<NN, 256, 0, stream>>>(snA, offA, s2, d2, zh, Phb, h2h);
  mfma_out<<<dim3(2, 313), 256, 0, stream>>>(h2h, Wc2t, bc2, out_p, NN);
}